// Round 1
// baseline (436.193 us; speedup 1.0000x reference)
//
#include <hip/hip_runtime.h>

#define HH 512
#define WW 512
#define HW (512*512)
#define NB 8
#define ND 16
#define RR 5
#define KK 11
#define TS 32

__device__ __forceinline__ int reflect(int v) {
    // valid for v in (-H, 2H-1); here v in [-10, 521]
    if (v < 0) v = -v;
    if (v >= HH) v = 2*HH - 2 - v;
    return v;
}

// ---------------- Prepass: mean_I and 1/(var_I + eps), per image ----------------
__global__ __launch_bounds__(256) void img_stats(const float* __restrict__ img,
                                                 float* __restrict__ meanI,
                                                 float* __restrict__ invv) {
    const int E1 = TS + 2*RR;   // 42
    const int P1 = E1 + 1;      // 43 (odd pitch -> <=2-way LDS banking)
    const int PH = TS + 1;      // 33
    __shared__ float sI[E1*P1], sI2[E1*P1];
    __shared__ float hI[E1*PH], hI2[E1*PH];

    int blk  = blockIdx.x;
    int tile = blk & 255;       // 16x16 tiles of 32x32
    int b    = blk >> 8;
    int ty0  = (tile >> 4) * TS;
    int tx0  = (tile & 15) * TS;
    const float* ib = img + b*HW;
    const float inv11 = 1.0f/11.0f;

    for (int i = threadIdx.x; i < E1*E1; i += 256) {
        int y = i / E1, x = i % E1;
        int gy = reflect(ty0 - RR + y);
        int gx = reflect(tx0 - RR + x);
        float v = ib[gy*WW + gx];
        sI [y*P1 + x] = v;
        sI2[y*P1 + x] = v*v;
    }
    __syncthreads();
    for (int i = threadIdx.x; i < E1*TS; i += 256) {
        int y = i / TS, x = i % TS;
        float s0 = 0.f, s1 = 0.f;
        #pragma unroll
        for (int dx = 0; dx < KK; ++dx) { s0 += sI[y*P1+x+dx]; s1 += sI2[y*P1+x+dx]; }
        hI [y*PH + x] = s0 * inv11;
        hI2[y*PH + x] = s1 * inv11;
    }
    __syncthreads();
    for (int i = threadIdx.x; i < TS*TS; i += 256) {
        int y = i / TS, x = i % TS;
        float s0 = 0.f, s1 = 0.f;
        #pragma unroll
        for (int dy = 0; dy < KK; ++dy) { s0 += hI[(y+dy)*PH+x]; s1 += hI2[(y+dy)*PH+x]; }
        float mI  = s0 * inv11;
        float mII = s1 * inv11;
        float var = mII - mI*mI;
        int gy = ty0 + y, gx = tx0 + x;
        meanI[b*HW + gy*WW + gx] = mI;
        invv [b*HW + gy*WW + gx] = 1.0f / (var + 1e-8f);
    }
}

// ---------------- Main fused kernel: one (b,d) channel, one 32x32 tile ----------------
__global__ __launch_bounds__(256) void guided_main(const float* __restrict__ feat,
                                                   const float* __restrict__ img,
                                                   const float* __restrict__ meanI,
                                                   const float* __restrict__ invv,
                                                   float* __restrict__ out) {
    const int E2 = TS + 4*RR;   // 52 : load extent (halo 10)
    const int E1 = TS + 2*RR;   // 42 : a,b extent (halo 5)
    const int P2 = E2 + 1;      // 53
    const int P1 = E1 + 1;      // 43
    __shared__ float sF[E2*P2];   // feat tile; reused for a
    __shared__ float sP[E2*P2];   // img*feat tile; reused for b
    __shared__ float hF[E2*P1];   // h-blurred feat; reused for h-blurred a
    __shared__ float hP[E2*P1];   // h-blurred img*feat; reused for h-blurred b

    int blk  = blockIdx.x;
    int tile = blk & 255;
    int bd   = blk >> 8;
    int b    = bd >> 4;
    int ty0  = (tile >> 4) * TS;
    int tx0  = (tile & 15) * TS;

    const float inv11 = 1.0f/11.0f;
    const float* fb  = feat  + bd*HW;
    const float* ib  = img   + b*HW;
    const float* mIb = meanI + b*HW;
    const float* ivb = invv  + b*HW;

    // Phase 1: load feat and img*feat over [E2][E2] (reflect-padded coords)
    for (int i = threadIdx.x; i < E2*E2; i += 256) {
        int y = i / E2, x = i % E2;
        int gy = reflect(ty0 - 2*RR + y);
        int gx = reflect(tx0 - 2*RR + x);
        float f  = fb[gy*WW + gx];
        float im = ib[gy*WW + gx];
        sF[y*P2 + x] = f;
        sP[y*P2 + x] = f * im;
    }
    __syncthreads();

    // Phase 2: horizontal blur -> [E2 rows][E1 cols]
    for (int i = threadIdx.x; i < E2*E1; i += 256) {
        int y = i / E1, x = i % E1;
        float s0 = 0.f, s1 = 0.f;
        #pragma unroll
        for (int dx = 0; dx < KK; ++dx) { s0 += sF[y*P2+x+dx]; s1 += sP[y*P2+x+dx]; }
        hF[y*P1 + x] = s0 * inv11;
        hP[y*P1 + x] = s1 * inv11;
    }
    __syncthreads();

    // Phase 3: vertical blur -> mean_p, corr_Ip at [E1][E1]; compute a,b (reuse sF,sP)
    for (int i = threadIdx.x; i < E1*E1; i += 256) {
        int y = i / E1, x = i % E1;
        float s0 = 0.f, s1 = 0.f;
        #pragma unroll
        for (int dy = 0; dy < KK; ++dy) { s0 += hF[(y+dy)*P1+x]; s1 += hP[(y+dy)*P1+x]; }
        float mp  = s0 * inv11;
        float cip = s1 * inv11;
        int gy = reflect(ty0 - RR + y);
        int gx = reflect(tx0 - RR + x);
        float mI = mIb[gy*WW + gx];
        float iv = ivb[gy*WW + gx];
        float a  = (cip - mI*mp) * iv;
        float bb = mp - a*mI;
        sF[y*P2 + x] = a;
        sP[y*P2 + x] = bb;
    }
    __syncthreads();

    // Phase 4: horizontal blur of a,b -> [E1 rows][TS cols] (reuse hF,hP)
    for (int i = threadIdx.x; i < E1*TS; i += 256) {
        int y = i / TS, x = i % TS;
        float s0 = 0.f, s1 = 0.f;
        #pragma unroll
        for (int dx = 0; dx < KK; ++dx) { s0 += sF[y*P2+x+dx]; s1 += sP[y*P2+x+dx]; }
        hF[y*P1 + x] = s0 * inv11;
        hP[y*P1 + x] = s1 * inv11;
    }
    __syncthreads();

    // Phase 5: vertical blur -> mean_a, mean_b at [TS][TS]; combine and store
    for (int i = threadIdx.x; i < TS*TS; i += 256) {
        int y = i / TS, x = i % TS;
        float s0 = 0.f, s1 = 0.f;
        #pragma unroll
        for (int dy = 0; dy < KK; ++dy) { s0 += hF[(y+dy)*P1+x]; s1 += hP[(y+dy)*P1+x]; }
        float ma = s0 * inv11;
        float mb = s1 * inv11;
        int gy = ty0 + y, gx = tx0 + x;
        float im = ib[gy*WW + gx];
        out[bd*HW + gy*WW + gx] = ma*im + mb;
    }
}

extern "C" void kernel_launch(void* const* d_in, const int* in_sizes, int n_in,
                              void* d_out, int out_size, void* d_ws, size_t ws_size,
                              hipStream_t stream) {
    const float* feat = (const float*)d_in[0];
    const float* img  = (const float*)d_in[1];
    float* out   = (float*)d_out;
    float* meanI = (float*)d_ws;              // NB*HW floats = 8 MiB
    float* invv  = meanI + (size_t)NB*HW;     // 8 MiB more

    img_stats<<<NB*256, 256, 0, stream>>>(img, meanI, invv);
    guided_main<<<(NB*ND)*256, 256, 0, stream>>>(feat, img, meanI, invv, out);
}

// Round 2
// 333.661 us; speedup vs baseline: 1.3073x; 1.3073x over previous
//
#include <hip/hip_runtime.h>

#define HH 512
#define WW 512
#define HW (512*512)
#define NB 8
#define ND 16
#define RR 5
#define KK 11
#define TS 32
#define E2 52
#define E1 42
#define P2 53
#define P1 43

__device__ __forceinline__ int reflect(int v) {
    // valid for v in (-H, 2H-1); here v in [-10, 521]
    if (v < 0) v = -v;
    if (v >= HH) v = 2*HH - 2 - v;
    return v;
}

// ---------------- Prepass: mean_I and 1/(var_I + eps), per image ----------------
__global__ __launch_bounds__(256) void img_stats(const float* __restrict__ img,
                                                 float* __restrict__ meanI,
                                                 float* __restrict__ invv) {
    const int EE = TS + 2*RR;   // 42
    const int PP = EE + 1;      // 43
    const int PH = TS + 1;      // 33
    __shared__ float sI[EE*PP], sI2[EE*PP];
    __shared__ float hI[EE*PH], hI2[EE*PH];

    int blk  = blockIdx.x;
    int tile = blk & 255;
    int b    = blk >> 8;
    int ty0  = (tile >> 4) * TS;
    int tx0  = (tile & 15) * TS;
    const float* ib = img + (size_t)b*HW;
    const float inv121 = 1.0f/121.0f;

    for (int i = threadIdx.x; i < EE*EE; i += 256) {
        int y = i / EE, x = i - y*EE;
        int gy = reflect(ty0 - RR + y);
        int gx = reflect(tx0 - RR + x);
        float v = ib[gy*WW + gx];
        sI [y*PP + x] = v;
        sI2[y*PP + x] = v*v;
    }
    __syncthreads();
    // h-sums: 42 rows x 2 arrays x 2 segs(16) = 168 jobs
    if (threadIdx.x < 168) {
        int t = threadIdx.x;
        int arr = t / 84, r2 = t - arr*84;
        int seg = r2 / 42, row = r2 - seg*42;
        const float* sr = (arr ? sI2 : sI) + row*PP;
        float* dr = (arr ? hI2 : hI) + row*PH;
        int x0 = seg*16;
        float s = 0.f;
        #pragma unroll
        for (int j = 0; j < 10; ++j) s += sr[x0+j];
        #pragma unroll
        for (int x = 0; x < 16; ++x) {
            s += sr[x0+x+10];
            dr[x0+x] = s;
            s -= sr[x0+x];
        }
    }
    __syncthreads();
    // v-sums + stats: 32 cols x 2 arrays x 4 segs(8) = 256 jobs -> reuse sI/sI2
    {
        int t = threadIdx.x;
        int arr = t >> 7, r2 = t & 127;
        int seg = r2 >> 5, col = r2 & 31;
        const float* src = arr ? hI2 : hI;
        float* dst = arr ? sI2 : sI;
        int y0 = seg*8;
        float s = 0.f;
        #pragma unroll
        for (int j = 0; j < 10; ++j) s += src[(y0+j)*PH+col];
        #pragma unroll
        for (int k = 0; k < 8; ++k) {
            int y = y0 + k;
            s += src[(y+10)*PH+col];
            dst[y*PP+col] = s;
            s -= src[y*PH+col];
        }
    }
    __syncthreads();
    for (int i = threadIdx.x; i < TS*TS; i += 256) {
        int y = i >> 5, x = i & 31;
        float mI  = sI [y*PP+x]*inv121;
        float mII = sI2[y*PP+x]*inv121;
        float var = mII - mI*mI;
        int gy = ty0 + y, gx = tx0 + x;
        meanI[(size_t)b*HW + gy*WW + gx] = mI;
        invv [(size_t)b*HW + gy*WW + gx] = 1.0f / (var + 1e-8f);
    }
}

// ---------------- Main fused kernel: one (b,d) channel, one 32x32 tile ----------------
__global__ __launch_bounds__(256) void guided_main(const float* __restrict__ feat,
                                                   const float* __restrict__ img,
                                                   const float* __restrict__ meanI,
                                                   const float* __restrict__ invv,
                                                   float* __restrict__ out) {
    __shared__ float sF[E2*P2];   // feat tile; later v-sums; later a h-sums
    __shared__ float sP[E2*P2];
    __shared__ float hF[E2*P1];   // h-sums; later a,b; later final v-sums
    __shared__ float hP[E2*P1];

    int blk  = blockIdx.x;
    int tile = blk & 255;
    int bd   = blk >> 8;
    int b    = bd >> 4;
    int ty0  = (tile >> 4) * TS;
    int tx0  = (tile & 15) * TS;

    const float inv121 = 1.0f/121.0f;
    const float* fb  = feat  + (size_t)bd*HW;
    const float* ib  = img   + (size_t)b*HW;
    const float* mIb = meanI + (size_t)b*HW;
    const float* ivb = invv  + (size_t)b*HW;
    const int t = threadIdx.x;

    // Phase 1: load feat and img*feat over [52][52]
    for (int i = t; i < E2*E2; i += 256) {
        int y = i / E2, x = i - y*E2;
        int gy = reflect(ty0 - 2*RR + y);
        int gx = reflect(tx0 - 2*RR + x);
        float f  = fb[gy*WW + gx];
        float im = ib[gy*WW + gx];
        sF[y*P2 + x] = f;
        sP[y*P2 + x] = f * im;
    }
    __syncthreads();

    // Phase 2: raw h-sums -> hF/hP [52 rows][42 cols]; 52r x 2arr x 2seg(21) = 208 jobs
    if (t < 208) {
        int arr = t / 104, r2 = t - arr*104;
        int seg = r2 / 52, row = r2 - seg*52;
        const float* sr = (arr ? sP : sF) + row*P2;
        float* dr = (arr ? hP : hF) + row*P1;
        int x0 = seg*21;
        float s = 0.f;
        #pragma unroll
        for (int j = 0; j < 10; ++j) s += sr[x0+j];
        #pragma unroll
        for (int x = 0; x < 21; ++x) {
            s += sr[x0+x+10];
            dr[x0+x] = s;
            s -= sr[x0+x];
        }
    }
    __syncthreads();

    // Phase 3: raw v-sums -> sF/sP [42][42] (pitch P2); 42c x 2arr x 3seg(14) = 252 jobs
    if (t < 252) {
        int arr = t / 126, r2 = t - arr*126;
        int seg = r2 / 42, col = r2 - seg*42;
        const float* src = arr ? hP : hF;
        float* dst = arr ? sP : sF;
        int y0 = seg*14;
        float s = 0.f;
        #pragma unroll
        for (int j = 0; j < 10; ++j) s += src[(y0+j)*P1+col];
        #pragma unroll
        for (int k = 0; k < 14; ++k) {
            int y = y0 + k;
            s += src[(y+10)*P1+col];
            dst[y*P2+col] = s;
            s -= src[y*P1+col];
        }
    }
    __syncthreads();

    // Phase 3b: a,b at [42][42] -> hF/hP (pitch P1)
    for (int i = t; i < E1*E1; i += 256) {
        int y = i / E1, x = i - y*E1;
        float mp  = sF[y*P2+x]*inv121;
        float cip = sP[y*P2+x]*inv121;
        int gy = reflect(ty0 - RR + y);
        int gx = reflect(tx0 - RR + x);
        float mI = mIb[gy*WW + gx];
        float iv = ivb[gy*WW + gx];
        float a  = (cip - mI*mp) * iv;
        hF[y*P1+x] = a;
        hP[y*P1+x] = mp - a*mI;
    }
    __syncthreads();

    // Phase 4: h-sums of a,b -> sF/sP [42 rows][32 cols] (pitch P2); 42r x 2arr x 2seg(16) = 168
    if (t < 168) {
        int arr = t / 84, r2 = t - arr*84;
        int seg = r2 / 42, row = r2 - seg*42;
        const float* sr = (arr ? hP : hF) + row*P1;
        float* dr = (arr ? sP : sF) + row*P2;
        int x0 = seg*16;
        float s = 0.f;
        #pragma unroll
        for (int j = 0; j < 10; ++j) s += sr[x0+j];
        #pragma unroll
        for (int x = 0; x < 16; ++x) {
            s += sr[x0+x+10];
            dr[x0+x] = s;
            s -= sr[x0+x];
        }
    }
    __syncthreads();

    // Phase 5: v-sums -> hF/hP [32][32] (pitch P1); 32c x 2arr x 4seg(8) = 256 jobs
    {
        int arr = t >> 7, r2 = t & 127;
        int seg = r2 >> 5, col = r2 & 31;
        const float* src = arr ? sP : sF;
        float* dst = arr ? hP : hF;
        int y0 = seg*8;
        float s = 0.f;
        #pragma unroll
        for (int j = 0; j < 10; ++j) s += src[(y0+j)*P2+col];
        #pragma unroll
        for (int k = 0; k < 8; ++k) {
            int y = y0 + k;
            s += src[(y+10)*P2+col];
            dst[y*P1+col] = s;
            s -= src[y*P2+col];
        }
    }
    __syncthreads();

    // Phase 5b: combine and store
    float* ob = out + (size_t)bd*HW;
    for (int i = t; i < TS*TS; i += 256) {
        int y = i >> 5, x = i & 31;
        float ma = hF[y*P1+x]*inv121;
        float mb = hP[y*P1+x]*inv121;
        int gy = ty0 + y, gx = tx0 + x;
        ob[gy*WW + gx] = ma*ib[gy*WW + gx] + mb;
    }
}

extern "C" void kernel_launch(void* const* d_in, const int* in_sizes, int n_in,
                              void* d_out, int out_size, void* d_ws, size_t ws_size,
                              hipStream_t stream) {
    const float* feat = (const float*)d_in[0];
    const float* img  = (const float*)d_in[1];
    float* out   = (float*)d_out;
    float* meanI = (float*)d_ws;              // NB*HW floats = 8 MiB
    float* invv  = meanI + (size_t)NB*HW;     // 8 MiB more

    img_stats<<<NB*256, 256, 0, stream>>>(img, meanI, invv);
    guided_main<<<(NB*ND)*256, 256, 0, stream>>>(feat, img, meanI, invv, out);
}

// Round 3
// 250.561 us; speedup vs baseline: 1.7409x; 1.3317x over previous
//
#include <hip/hip_runtime.h>

#define HH 512
#define WW 512
#define HW (512*512)
#define NB 8
#define ND 16
#define RR 5
#define TS 64            // main tile 64x64
#define EX 84            // raw extent (halo 10)
#define EO 74            // first-blur output extent (halo 5)
#define PP 77            // LDS pitch (odd -> conflict-free columns)

__device__ __forceinline__ int reflect(int v) {
    if (v < 0) v = -v;
    if (v >= HH) v = 2*HH - 2 - v;
    return v;
}

// ---------------- Prepass: mean_I and 1/(var_I + eps), per image (32x32 tiles) ---------
__global__ __launch_bounds__(256) void img_stats(const float* __restrict__ img,
                                                 float* __restrict__ meanI,
                                                 float* __restrict__ invv) {
    const int EE = 42, Q = 43, PH = 33;
    __shared__ float sI[EE*Q], sI2[EE*Q];
    __shared__ float hI[EE*PH], hI2[EE*PH];

    int blk  = blockIdx.x;
    int tile = blk & 255;
    int b    = blk >> 8;
    int ty0  = (tile >> 4) * 32;
    int tx0  = (tile & 15) * 32;
    const float* ib = img + (size_t)b*HW;
    const float inv121 = 1.0f/121.0f;

    for (int i = threadIdx.x; i < EE*EE; i += 256) {
        int y = i / EE, x = i - y*EE;
        int gy = reflect(ty0 - RR + y);
        int gx = reflect(tx0 - RR + x);
        float v = ib[gy*WW + gx];
        sI [y*Q + x] = v;
        sI2[y*Q + x] = v*v;
    }
    __syncthreads();
    if (threadIdx.x < 168) {
        int t = threadIdx.x;
        int arr = t / 84, r2 = t - arr*84;
        int seg = r2 / 42, row = r2 - seg*42;
        const float* sr = (arr ? sI2 : sI) + row*Q;
        float* dr = (arr ? hI2 : hI) + row*PH;
        int x0 = seg*16;
        float s = 0.f;
        #pragma unroll
        for (int j = 0; j < 10; ++j) s += sr[x0+j];
        #pragma unroll
        for (int x = 0; x < 16; ++x) {
            s += sr[x0+x+10];
            dr[x0+x] = s;
            s -= sr[x0+x];
        }
    }
    __syncthreads();
    {
        int t = threadIdx.x;
        int arr = t >> 7, r2 = t & 127;
        int seg = r2 >> 5, col = r2 & 31;
        const float* src = arr ? hI2 : hI;
        float* dst = arr ? sI2 : sI;
        int y0 = seg*8;
        float s = 0.f;
        #pragma unroll
        for (int j = 0; j < 10; ++j) s += src[(y0+j)*PH+col];
        #pragma unroll
        for (int k = 0; k < 8; ++k) {
            int y = y0 + k;
            s += src[(y+10)*PH+col];
            dst[y*Q+col] = s;
            s -= src[y*PH+col];
        }
    }
    __syncthreads();
    for (int i = threadIdx.x; i < 32*32; i += 256) {
        int y = i >> 5, x = i & 31;
        float mI  = sI [y*Q+x]*inv121;
        float mII = sI2[y*Q+x]*inv121;
        float var = mII - mI*mI;
        int gy = ty0 + y, gx = tx0 + x;
        meanI[(size_t)b*HW + gy*WW + gx] = mI;
        invv [(size_t)b*HW + gy*WW + gx] = 1.0f / (var + 1e-8f);
    }
}

// ---------------- Main fused kernel: one (b,d) channel, one 64x64 tile -----------------
// LDS: only h-sum buffers [EX][PP] x2. Register ring buffers for all sliding sums.
// a,b are written in-place into the h-sum buffers at row slot(r) = r + 10*(r>=37):
// per column, seg0 writes slots 0..36 / reads rows 0..46; seg1 writes 47..83 / reads
// 37..83 -> no overlap either way, and within-thread the write trails reads by 10 rows.
__global__ __launch_bounds__(192) void guided_main(const float* __restrict__ feat,
                                                   const float* __restrict__ img,
                                                   const float* __restrict__ meanI,
                                                   const float* __restrict__ invv,
                                                   float* __restrict__ out) {
    __shared__ float hF[EX*PP];
    __shared__ float hP[EX*PP];

    int blk  = blockIdx.x;
    int tile = blk & 63;         // 8x8 tiles of 64x64
    int bd   = blk >> 6;
    int b    = bd >> 4;
    int ty0  = (tile >> 3) * TS;
    int tx0  = (tile & 7)  * TS;

    const float inv121 = 1.0f/121.0f;
    const float* fb  = feat  + (size_t)bd*HW;
    const float* ib  = img   + (size_t)b*HW;
    const float* mIb = meanI + (size_t)b*HW;
    const float* ivb = invv  + (size_t)b*HW;
    const int t = threadIdx.x;

    // ---- Phase A: global rows -> horizontal raw 11-sums -> hF/hP [84][74] ----
    if (t < 168) {
        int seg = t / 84, row = t - seg*84;   // lanes: consecutive rows
        int gy = reflect(ty0 - 10 + row);
        const float* fr = fb + gy*WW;
        const float* ir = ib + gy*WW;
        int xb = seg*37;                      // outputs xb..xb+36
        float* dF = hF + row*PP + xb;
        float* dP = hP + row*PP + xb;
        float rf[11], rp[11];
        float sf = 0.f, sp = 0.f;
        #pragma unroll
        for (int j = 0; j < 10; ++j) {
            int gx = reflect(tx0 - 10 + xb + j);
            float f = fr[gx], p = f * ir[gx];
            rf[j] = f; rp[j] = p; sf += f; sp += p;
        }
        #pragma unroll
        for (int k = 0; k < 37; ++k) {
            int gx = reflect(tx0 + xb + k);   // = tx0-10+xb+k+10
            float f = fr[gx], p = f * ir[gx];
            sf += f; sp += p;
            dF[k] = sf; dP[k] = sp;
            sf -= rf[k%11]; sp -= rp[k%11];
            rf[(k+10)%11] = f; rp[(k+10)%11] = p;
        }
    }
    __syncthreads();

    // ---- Phase B: vertical 11-sums per column + a,b; write a,b in place ----
    if (t < 148) {
        int seg = t / 74, col = t - seg*74;   // lanes: consecutive cols
        int ybase = seg*37;                   // outputs ybase..ybase+36
        const float* cF = hF + col;
        const float* cP = hP + col;
        int gx = reflect(tx0 - 5 + col);
        float rf[11], rp[11];
        float sf = 0.f, sp = 0.f;
        #pragma unroll
        for (int j = 0; j < 10; ++j) {
            float f = cF[(ybase+j)*PP], p = cP[(ybase+j)*PP];
            rf[j] = f; rp[j] = p; sf += f; sp += p;
        }
        #pragma unroll
        for (int k = 0; k < 37; ++k) {
            int y = ybase + k;                // output row index (0..73)
            float f = cF[(y+10)*PP], p = cP[(y+10)*PP];
            sf += f; sp += p;
            float mp  = sf*inv121;
            float cip = sp*inv121;
            int gy = reflect(ty0 - 5 + y);
            float mI = mIb[gy*WW + gx];
            float iv = ivb[gy*WW + gx];
            float a  = (cip - mI*mp) * iv;
            float bb = mp - a*mI;
            int slot = y + 10*seg;            // slot map (see header comment)
            hF[slot*PP + col] = a;
            hP[slot*PP + col] = bb;
            sf -= rf[k%11]; sp -= rp[k%11];
            rf[(k+10)%11] = f; rp[(k+10)%11] = p;
        }
    }
    __syncthreads();

    // ---- Phase C: horizontal 11-sums of a,b, in place (cols 0..63 of each slot row) ----
    if (t < 148) {
        int arr = t / 74, r = t - arr*74;     // lanes: consecutive rows
        int slot = r + ((r >= 37) ? 10 : 0);
        float* rowp = (arr ? hP : hF) + slot*PP;
        float ring[11];
        float s = 0.f;
        #pragma unroll
        for (int j = 0; j < 10; ++j) { float v = rowp[j]; ring[j] = v; s += v; }
        #pragma unroll
        for (int k = 0; k < 64; ++k) {
            float v = rowp[k+10];
            s += v;
            float o = s;
            s -= ring[k%11];
            ring[(k+10)%11] = v;
            rowp[k] = o;                      // write trails reads by 10 cols
        }
    }
    __syncthreads();

    // ---- Phase D: vertical 11-sums + combine + store ----
    if (t < 128) {
        int seg = t >> 6, col = t & 63;       // lanes: consecutive cols
        int ybase = seg*32;                   // outputs ybase..ybase+31
        float ra[11], rb[11];
        float sa = 0.f, sb = 0.f;
        #pragma unroll
        for (int j = 0; j < 10; ++j) {
            int y = ybase + j; int slot = y + ((y >= 37) ? 10 : 0);
            float av = hF[slot*PP+col], bv = hP[slot*PP+col];
            ra[j] = av; rb[j] = bv; sa += av; sb += bv;
        }
        float* ob = out + (size_t)bd*HW;
        #pragma unroll
        for (int k = 0; k < 32; ++k) {
            int y = ybase + k + 10; int slot = y + ((y >= 37) ? 10 : 0);
            float av = hF[slot*PP+col], bv = hP[slot*PP+col];
            sa += av; sb += bv;
            int gy = ty0 + ybase + k, gx = tx0 + col;
            float im = ib[gy*WW + gx];
            ob[gy*WW + gx] = (sa*im + sb)*inv121;
            sa -= ra[k%11]; sb -= rb[k%11];
            ra[(k+10)%11] = av; rb[(k+10)%11] = bv;
        }
    }
}

extern "C" void kernel_launch(void* const* d_in, const int* in_sizes, int n_in,
                              void* d_out, int out_size, void* d_ws, size_t ws_size,
                              hipStream_t stream) {
    const float* feat = (const float*)d_in[0];
    const float* img  = (const float*)d_in[1];
    float* out   = (float*)d_out;
    float* meanI = (float*)d_ws;              // NB*HW floats = 8 MiB
    float* invv  = meanI + (size_t)NB*HW;     // 8 MiB more

    img_stats<<<NB*256, 256, 0, stream>>>(img, meanI, invv);
    guided_main<<<NB*ND*64, 192, 0, stream>>>(feat, img, meanI, invv, out);
}